// Round 3
// baseline (22879.932 us; speedup 1.0000x reference)
//
#include <hip/hip_runtime.h>
#include <hip/hip_cooperative_groups.h>
#include <hip/hip_bf16.h>
#include <cstdint>
#include <cstddef>

namespace cg = cooperative_groups;

namespace {

constexpr int S_LEN  = 256;
constexpr int BATCH  = 256;
constexpr int NH     = 512;
constexpr int NE     = 256;
constexpr int NSTEPS = 127;          // TGT_LEN-1
constexpr int N1     = 2048;         // [Wo;Wz;Wr;Wn_partial]
constexpr size_t SB        = (size_t)S_LEN * BATCH;   // 65536
constexpr size_t SRC_ELEMS = SB * NH;                 // 33,554,432

typedef __attribute__((ext_vector_type(8))) short  short8v;
typedef __attribute__((ext_vector_type(4))) float  float4v;
typedef unsigned short us;

constexpr int EPI_F32 = 0, EPI_EPROJ = 1, EPI_STEP1 = 2, EPI_STEP2 = 3, EPI_S0 = 4;

__device__ __forceinline__ float bf2f(us u) {
  union { unsigned int i; float f; } c; c.i = ((unsigned int)u) << 16; return c.f;
}
__device__ __forceinline__ us f2bf(float f) {
  union { float f; unsigned int i; } c; c.f = f;
  unsigned int x = c.i;
  return (us)((x + 0x7FFFu + ((x >> 16) & 1u)) >> 16);
}
// tanh(x) = 1 - 2/(e^{2x}+1)
__device__ __forceinline__ float tanh2(float x) {
  return 1.f - 2.f * __builtin_amdgcn_rcpf(__expf(2.f * x) + 1.f);
}
__device__ __forceinline__ float sigm(float x) {
  return __builtin_amdgcn_rcpf(1.f + __expf(-x));
}

// ---------------- prologue: conversions ----------------

// src_enc (S,B,H) f32 -> src_t (B,S,H) bf16
__global__ void k_conv_src(const float* __restrict__ src, us* __restrict__ dst) {
  const int total = S_LEN * BATCH * 64;       // 8-elem chunks, dest-linear
  int i = blockIdx.x * blockDim.x + threadIdx.x;
  int stride = gridDim.x * blockDim.x;
  for (; i < total; i += stride) {
    int c = i & 63, s = (i >> 6) & 255, b = i >> 14;
    const float* p = src + ((size_t)s * BATCH + b) * NH + c * 8;
    float4 v0 = *(const float4*)p;
    float4 v1 = *(const float4*)(p + 4);
    us o[8] = { f2bf(v0.x), f2bf(v0.y), f2bf(v0.z), f2bf(v0.w),
                f2bf(v1.x), f2bf(v1.y), f2bf(v1.z), f2bf(v1.w) };
    *(short8v*)(dst + (size_t)i * 8) = *(const short8v*)o;
  }
}

__global__ void k_conv_w(const float* __restrict__ Wo, const float* __restrict__ Wz,
                         const float* __restrict__ Wr, const float* __restrict__ Wn,
                         const float* __restrict__ Wa, const float* __restrict__ Ws,
                         const float* __restrict__ Wob, const float* __restrict__ Wzb,
                         const float* __restrict__ Wrb, const float* __restrict__ Wnb,
                         us* __restrict__ W1cat, us* __restrict__ Wns,
                         us* __restrict__ Was, us* __restrict__ Wae,
                         us* __restrict__ Wsbf, float* __restrict__ bcat) {
  const int T1 = 2048 * 1280;
  const int T2 = 512 * 512;
  const int total = T1 + 4 * T2 + 2048;
  int i = blockIdx.x * blockDim.x + threadIdx.x;
  int stride = gridDim.x * blockDim.x;
  for (; i < total; i += stride) {
    int idx = i;
    if (idx < T1) {
      int row = idx / 1280, col = idx - row * 1280;
      float v;
      if      (row < 512)  v = Wo[row * 1280 + col];
      else if (row < 1024) v = Wz[(row - 512) * 1280 + col];
      else if (row < 1536) v = Wr[(row - 1024) * 1280 + col];
      else {
        int g = row - 1536;
        v = (col >= 256 && col < 768) ? 0.f : Wn[g * 1280 + col];
      }
      W1cat[idx] = f2bf(v);
    } else if ((idx -= T1) < T2) {
      int g = idx >> 9, j = idx & 511;
      Wns[idx] = f2bf(Wn[g * 1280 + 256 + j]);
    } else if ((idx -= T2) < T2) {
      int g = idx >> 9, h = idx & 511;
      Was[idx] = f2bf(Wa[g * 1024 + h]);
    } else if ((idx -= T2) < T2) {
      int g = idx >> 9, h = idx & 511;
      Wae[idx] = f2bf(Wa[g * 1024 + 512 + h]);
    } else if ((idx -= T2) < T2) {
      Wsbf[idx] = f2bf(Ws[idx]);
    } else {
      idx -= T2;
      bcat[idx] = (idx < 512) ? Wob[idx]
                : (idx < 1024) ? Wzb[idx - 512]
                : (idx < 1536) ? Wrb[idx - 1024]
                               : Wnb[idx - 1536];
    }
  }
}

__global__ void k_emb(const int* __restrict__ tgt, const float* __restrict__ table,
                      us* __restrict__ emb) {
  const int total = NSTEPS * BATCH * NE;
  int i = blockIdx.x * blockDim.x + threadIdx.x;
  int stride = gridDim.x * blockDim.x;
  for (; i < total; i += stride) {
    int e  = i & (NE - 1);
    int tb = i >> 8;
    int sym = tgt[tb];
    emb[i] = f2bf(table[sym * NE + e]);
  }
}

// ---------------- 8-wave MFMA GEMM tile: 64 rows x 128 cols, BK=64 ----------------
// C[m,n] = sum_k A[m,k] * B[n,k]   (A,B bf16 row-major over K)
template<int EPI>
__device__ __forceinline__ void gemm_tile(
    char* smem, int m0, int n0,
    const us* __restrict__ A0, const us* __restrict__ A1, const us* __restrict__ A2,
    int lda, const us* __restrict__ Bw, int ldb, int K,
    const float* __restrict__ bias, float* __restrict__ f0, float* __restrict__ f1,
    float* __restrict__ f2, us* __restrict__ g0, const float* __restrict__ sf) {
  const int tid = threadIdx.x;
  char* As0 = smem;               // 2 x 8192
  char* Bs0 = smem + 16384;       // 2 x 16384
  const int arow = tid >> 3, ac = (tid & 7) * 8;     // A: 64 rows x 64 cols
  const int brow = tid >> 2, bc = (tid & 3) * 16;    // B: 128 rows x 64 cols
  short8v ar, br0, br1;

  auto loadT = [&](int k0) {
    if (EPI == EPI_STEP1) {
      const int cc = k0 + ac;
      const us* p = (cc < 256) ? A0 + (size_t)(m0 + arow) * 256 + cc
                  : (cc < 768) ? A1 + (size_t)(m0 + arow) * 512 + (cc - 256)
                               : A2 + (size_t)(m0 + arow) * 512 + (cc - 768);
      ar = *(const short8v*)p;
    } else {
      ar = *(const short8v*)(A0 + (size_t)(m0 + arow) * lda + (k0 + ac));
    }
    const us* q = Bw + (size_t)(n0 + brow) * ldb + (k0 + bc);
    br0 = *(const short8v*)q;
    br1 = *(const short8v*)(q + 8);
  };
  auto stage = [&](int buf) {
    *(short8v*)(As0 + buf * 8192 + arow * 128 + ((ac * 2) ^ ((arow & 7) << 4))) = ar;
    char* bb = Bs0 + buf * 16384 + brow * 128;
    const int sw = (brow & 7) << 4;
    *(short8v*)(bb + ((bc * 2) ^ sw)) = br0;
    *(short8v*)(bb + ((bc * 2 + 16) ^ sw)) = br1;
  };

  const int lane = tid & 63, wave = tid >> 6;
  const int wm = (wave >> 2) * 32, wn = (wave & 3) * 32;
  const int fr = lane & 15, kq = lane >> 4;
  const int ra0 = wm + fr, ra1 = ra0 + 16;
  const int rb0 = wn + fr, rb1 = rb0 + 16;
  float4v acc00 = {0,0,0,0}, acc01 = {0,0,0,0}, acc10 = {0,0,0,0}, acc11 = {0,0,0,0};

  loadT(0);
  stage(0);
  const int nit = K >> 6;
  for (int it = 0; it < nit; ++it) {
    __syncthreads();
    if (it + 1 < nit) loadT((it + 1) << 6);
    const char* ab = As0 + (it & 1) * 8192;
    const char* bb = Bs0 + (it & 1) * 16384;
    #pragma unroll
    for (int ks = 0; ks < 2; ++ks) {
      const int cb = ks * 64 + kq * 16;
      short8v a0 = *(const short8v*)(ab + ra0 * 128 + (cb ^ ((ra0 & 7) << 4)));
      short8v a1 = *(const short8v*)(ab + ra1 * 128 + (cb ^ ((ra1 & 7) << 4)));
      short8v b0 = *(const short8v*)(bb + rb0 * 128 + (cb ^ ((rb0 & 7) << 4)));
      short8v b1 = *(const short8v*)(bb + rb1 * 128 + (cb ^ ((rb1 & 7) << 4)));
      acc00 = __builtin_amdgcn_mfma_f32_16x16x32_bf16(a0, b0, acc00, 0, 0, 0);
      acc01 = __builtin_amdgcn_mfma_f32_16x16x32_bf16(a0, b1, acc01, 0, 0, 0);
      acc10 = __builtin_amdgcn_mfma_f32_16x16x32_bf16(a1, b0, acc10, 0, 0, 0);
      acc11 = __builtin_amdgcn_mfma_f32_16x16x32_bf16(a1, b1, acc11, 0, 0, 0);
    }
    if (it + 1 < nit) stage((it + 1) & 1);
  }

  #pragma unroll
  for (int am = 0; am < 2; ++am) {
    #pragma unroll
    for (int bn = 0; bn < 2; ++bn) {
      float4v a = am ? (bn ? acc11 : acc10) : (bn ? acc01 : acc00);
      #pragma unroll
      for (int r = 0; r < 4; ++r) {
        const int rowO = m0 + wm + am * 16 + kq * 4 + r;
        const int colO = n0 + wn + bn * 16 + fr;
        float v = a[r];
        if (EPI == EPI_F32) {
          f0[(size_t)rowO * 512 + colO] = v;
        } else if (EPI == EPI_S0) {
          float tv = tanh2(v + bias[colO]);
          f0[(size_t)rowO * 512 + colO] = tv;
          g0[(size_t)rowO * 512 + colO] = f2bf(tv);
        } else if (EPI == EPI_EPROJ) {
          g0[(size_t)rowO * 512 + colO] = f2bf(v + bias[colO]);
        } else if (EPI == EPI_STEP1) {
          v += bias[colO];
          const int q = colO >> 9, j = colO & 511;
          const size_t idx = (size_t)rowO * 512 + j;
          if      (q == 0) f0[idx] = v;                       // dec_outputs[t]
          else if (q == 1) f1[idx] = sigm(v);                 // zi
          else if (q == 2) g0[idx] = f2bf(sigm(v) * sf[idx]); // xn = ri*s
          else             f2[idx] = v;                       // npart (incl Wn_b)
        } else { // EPI_STEP2
          const size_t idx = (size_t)rowO * 512 + colO;
          float nv = tanh2(v + f2[idx]);
          float z  = bias[idx];
          float so = f1[idx];
          float sn = (1.f - z) * so + z * nv;
          f0[idx] = so;                 // dec_states[t]
          f1[idx] = sn;                 // s_f32 (new)
          g0[idx] = f2bf(sn);           // s_bf
        }
      }
    }
  }
}

template<int EPI>
__global__ __launch_bounds__(512, 2) void k_gemm(
    const us* __restrict__ A0, int lda, const us* __restrict__ Bw, int ldb, int K,
    const float* __restrict__ bias, float* __restrict__ f0, us* __restrict__ g0) {
  __shared__ alignas(16) char smem[49152];
  gemm_tile<EPI>(smem, blockIdx.x * 64, blockIdx.y * 128,
                 A0, nullptr, nullptr, lda, Bw, ldb, K,
                 bias, f0, nullptr, nullptr, g0, nullptr);
}

// ---------------- persistent cooperative kernel: all 127 steps ----------------
struct KArgs {
  const us* src_t; const us* ep_t; const us* emb_bf;
  const us* W1cat; const us* Wns; const us* Was;
  const float* bcat; const float* vaw; const int* slen;
  us* s_bf; float* s_f32; float* sWa; float* zi; float* npart;
  us* xn_bf; us* ci_bf;
  float* dec_outputs; float* dec_states; float* dec_attns;
};

__global__ __launch_bounds__(512, 2) void k_steps(KArgs a) {
  __shared__ alignas(16) char smem[49152];
  cg::grid_group grid = cg::this_grid();
  const int blk = blockIdx.x, tid = threadIdx.x;
  const int lane = tid & 63, wave = tid >> 6, g0l = lane * 8;
  const int b = blk;
  const int len = a.slen[b];

  // hoisted attention constants: vv2 = 2*va slice, sumv = sum(va)
  float vv2[8]; float sumv = 0.f;
  {
    const float* vp = a.vaw + g0l;
    #pragma unroll
    for (int j = 0; j < 8; j++) { vv2[j] = 2.f * vp[j]; sumv += vp[j]; }
    #pragma unroll
    for (int off = 32; off > 0; off >>= 1) sumv += __shfl_xor(sumv, off, 64);
  }

  for (int t = 0; t < NSTEPS; ++t) {
    // ---- Phase A: sWa = s_bf @ Was^T  (16 blocks) ----
    if (blk < 16) {
      gemm_tile<EPI_F32>(smem, (blk >> 2) * 64, (blk & 3) * 128,
                         a.s_bf, nullptr, nullptr, 512, a.Was, 512, 512,
                         nullptr, a.sWa, nullptr, nullptr, nullptr, nullptr);
    }
    grid.sync();

    // ---- Phase B: attention for batch b (all 256 blocks) ----
    {
      float* ei   = (float*)smem;            // 256
      float* ai   = ei + 256;                // 256
      float* red  = ai + 256;                // 8
      float* red8 = (float*)(smem + 4096);   // 8*512

      float q2[8];
      {
        const float* qp = a.sWa + b * NH + g0l;
        #pragma unroll
        for (int j = 0; j < 8; j++) q2[j] = 2.f * qp[j];
      }
      // scores: ei[s] = sumv - sum_h 2*va[h] / (e^{2(ep+q)}+1)
      const us* epb = a.ep_t + ((size_t)b * S_LEN + wave) * NH + g0l;
      for (int s = wave; s < S_LEN; s += 8, epb += 8 * NH) {
        short8v v = *(const short8v*)epb;
        float acc = 0.f;
        #pragma unroll
        for (int j = 0; j < 8; j++) {
          float arg = __builtin_fmaf(bf2f((us)v[j]), 2.f, q2[j]);
          acc = __builtin_fmaf(vv2[j],
                __builtin_amdgcn_rcpf(__expf(arg) + 1.f), acc);
        }
        #pragma unroll
        for (int off = 32; off > 0; off >>= 1) acc += __shfl_xor(acc, off, 64);
        if (lane == 0) ei[s] = (s < len) ? (sumv - acc) : -3.0e38f;
      }
      __syncthreads();

      // softmax over s
      float e = (tid < S_LEN) ? ei[tid] : -3.0e38f;
      float m = e;
      #pragma unroll
      for (int off = 32; off > 0; off >>= 1) m = fmaxf(m, __shfl_xor(m, off, 64));
      if (lane == 0) red[wave] = m;
      __syncthreads();
      m = red[0];
      #pragma unroll
      for (int w = 1; w < 8; w++) m = fmaxf(m, red[w]);
      float p = (tid < S_LEN) ? __expf(e - m) : 0.f;
      float sum = p;
      #pragma unroll
      for (int off = 32; off > 0; off >>= 1) sum += __shfl_xor(sum, off, 64);
      __syncthreads();
      if (lane == 0) red[wave] = sum;
      __syncthreads();
      float tot = red[0];
      #pragma unroll
      for (int w = 1; w < 8; w++) tot += red[w];
      float inv = __builtin_amdgcn_rcpf(tot);
      if (tid < S_LEN) {
        float av = p * inv;
        ai[tid] = av;
        a.dec_attns[((size_t)t * BATCH + b) * S_LEN + tid] = av;
      }
      __syncthreads();

      // context: vectorized, wave-per-s, cross-wave LDS reduce
      float acc8[8] = {0,0,0,0,0,0,0,0};
      const us* sb = a.src_t + ((size_t)b * S_LEN + wave) * NH + g0l;
      for (int s = wave; s < S_LEN; s += 8, sb += 8 * NH) {
        short8v v = *(const short8v*)sb;
        float av = ai[s];
        #pragma unroll
        for (int j = 0; j < 8; j++)
          acc8[j] = __builtin_fmaf(av, bf2f((us)v[j]), acc8[j]);
      }
      #pragma unroll
      for (int j = 0; j < 8; j++) red8[wave * NH + g0l + j] = acc8[j];
      __syncthreads();
      float cv = 0.f;
      #pragma unroll
      for (int w = 0; w < 8; w++) cv += red8[w * NH + tid];
      a.ci_bf[b * NH + tid] = f2bf(cv);
    }
    grid.sync();

    // ---- Phase C: STEP1  Y = [emb|s|ci] @ W1cat^T + bcat (64 blocks) ----
    if (blk < 64) {
      gemm_tile<EPI_STEP1>(smem, (blk >> 4) * 64, (blk & 15) * 128,
                           a.emb_bf + (size_t)t * BATCH * NE, a.s_bf, a.ci_bf, 0,
                           a.W1cat, 1280, 1280,
                           a.bcat, a.dec_outputs + (size_t)t * BATCH * NH,
                           a.zi, a.npart, a.xn_bf, a.s_f32);
    }
    grid.sync();

    // ---- Phase D: STEP2  npre = npart + xn @ Wns^T; state update (16 blocks) ----
    if (blk < 16) {
      gemm_tile<EPI_STEP2>(smem, (blk >> 2) * 64, (blk & 3) * 128,
                           a.xn_bf, nullptr, nullptr, 512, a.Wns, 512, 512,
                           a.zi, a.dec_states + (size_t)t * BATCH * NH,
                           a.s_f32, a.npart, a.s_bf, nullptr);
    }
    grid.sync();
  }
}

} // namespace

extern "C" void kernel_launch(void* const* d_in, const int* in_sizes, int n_in,
                              void* d_out, int out_size, void* d_ws, size_t ws_size,
                              hipStream_t stream) {
  const float* src_enc  = (const float*)d_in[0];
  const int*   tgt      = (const int*)d_in[1];
  const int*   slen     = (const int*)d_in[2];
  const float* emb_tab  = (const float*)d_in[3];
  const float* Wsw      = (const float*)d_in[4];
  const float* Wsb      = (const float*)d_in[5];
  const float* Wzw      = (const float*)d_in[6];
  const float* Wzb      = (const float*)d_in[7];
  const float* Wrw      = (const float*)d_in[8];
  const float* Wrb      = (const float*)d_in[9];
  const float* Wnw      = (const float*)d_in[10];
  const float* Wnb      = (const float*)d_in[11];
  const float* Waw      = (const float*)d_in[12];
  const float* Wab      = (const float*)d_in[13];
  const float* vaw      = (const float*)d_in[14];
  const float* Wow      = (const float*)d_in[15];
  const float* Wob      = (const float*)d_in[16];

  char* ws = (char*)d_ws;
  size_t off = 0;
  auto alloc = [&](size_t bytes) -> void* {
    void* p = ws + off;
    off = (off + bytes + 255) & ~(size_t)255;
    return p;
  };
  us*    src_t  = (us*)alloc(SRC_ELEMS * 2);
  us*    ep_t   = (us*)alloc(SRC_ELEMS * 2);
  us*    emb_bf = (us*)alloc((size_t)NSTEPS * BATCH * NE * 2);
  us*    W1cat  = (us*)alloc((size_t)N1 * 1280 * 2);
  us*    Wns    = (us*)alloc((size_t)512 * 512 * 2);
  us*    Was    = (us*)alloc((size_t)512 * 512 * 2);
  us*    Wae    = (us*)alloc((size_t)512 * 512 * 2);
  us*    Wsbf   = (us*)alloc((size_t)512 * 512 * 2);
  float* bcat   = (float*)alloc((size_t)N1 * 4);
  float* s_f32  = (float*)alloc((size_t)BATCH * NH * 4);
  us*    s_bf   = (us*)alloc((size_t)BATCH * NH * 2);
  float* sWa    = (float*)alloc((size_t)BATCH * NH * 4);
  float* zi     = (float*)alloc((size_t)BATCH * NH * 4);
  float* npart  = (float*)alloc((size_t)BATCH * NH * 4);
  us*    xn_bf  = (us*)alloc((size_t)BATCH * NH * 2);
  us*    ci_bf  = (us*)alloc((size_t)BATCH * NH * 2);

  float* out         = (float*)d_out;
  float* dec_outputs = out;
  float* dec_states  = out + (size_t)NSTEPS * BATCH * NH;
  float* dec_attns   = dec_states + (size_t)NSTEPS * BATCH * NH;

  // ---- prologue ----
  k_conv_src<<<4096, 256, 0, stream>>>(src_enc, src_t);
  k_conv_w<<<2048, 256, 0, stream>>>(Wow, Wzw, Wrw, Wnw, Waw, Wsw,
                                     Wob, Wzb, Wrb, Wnb,
                                     W1cat, Wns, Was, Wae, Wsbf, bcat);
  k_emb<<<2048, 256, 0, stream>>>(tgt, emb_tab, emb_bf);
  // s0 = tanh(src_enc[0] @ Ws^T + Ws_b): rows b of src_t at stride S*NH
  k_gemm<EPI_S0><<<dim3(4, 4), 512, 0, stream>>>(
      src_t, S_LEN * NH, Wsbf, 512, 512, Wsb, s_f32, s_bf);
  // ep_t[b,s] = src_t[b,s] @ Wae^T + Wa_b
  k_gemm<EPI_EPROJ><<<dim3(1024, 4), 512, 0, stream>>>(
      src_t, 512, Wae, 512, 512, Wab, nullptr, ep_t);

  // ---- persistent cooperative kernel: all 127 steps ----
  KArgs a;
  a.src_t = src_t; a.ep_t = ep_t; a.emb_bf = emb_bf;
  a.W1cat = W1cat; a.Wns = Wns; a.Was = Was;
  a.bcat = bcat; a.vaw = vaw; a.slen = slen;
  a.s_bf = s_bf; a.s_f32 = s_f32; a.sWa = sWa; a.zi = zi; a.npart = npart;
  a.xn_bf = xn_bf; a.ci_bf = ci_bf;
  a.dec_outputs = dec_outputs; a.dec_states = dec_states; a.dec_attns = dec_attns;
  void* kargs[] = { &a };
  hipLaunchCooperativeKernel((const void*)k_steps, dim3(256), dim3(512),
                             kargs, 0, stream);
}

// Round 4
// 11330.744 us; speedup vs baseline: 2.0193x; 2.0193x over previous
//
#include <hip/hip_runtime.h>
#include <hip/hip_bf16.h>
#include <cstdint>
#include <cstddef>

namespace {

constexpr int S_LEN  = 256;
constexpr int BATCH  = 256;
constexpr int NH     = 512;
constexpr int NE     = 256;
constexpr int NSTEPS = 127;          // TGT_LEN-1
constexpr int N1     = 2048;         // [Wo;Wz;Wr;Wn_partial]
constexpr size_t SB        = (size_t)S_LEN * BATCH;   // 65536
constexpr size_t SRC_ELEMS = SB * NH;                 // 33,554,432

typedef __attribute__((ext_vector_type(8))) short  short8v;
typedef __attribute__((ext_vector_type(4))) float  float4v;
typedef unsigned short us;

constexpr int EPI_EPROJ = 1, EPI_STEP1 = 2, EPI_S0 = 4;

__device__ __forceinline__ float bf2f(us u) {
  union { unsigned int i; float f; } c; c.i = ((unsigned int)u) << 16; return c.f;
}
__device__ __forceinline__ us f2bf(float f) {
  union { float f; unsigned int i; } c; c.f = f;
  unsigned int x = c.i;
  return (us)((x + 0x7FFFu + ((x >> 16) & 1u)) >> 16);
}
// tanh(x) = 1 - 2/(e^{2x}+1)
__device__ __forceinline__ float tanh2(float x) {
  return 1.f - 2.f * __builtin_amdgcn_rcpf(__expf(2.f * x) + 1.f);
}
__device__ __forceinline__ float sigm(float x) {
  return __builtin_amdgcn_rcpf(1.f + __expf(-x));
}

// ---------------- prologue: conversions ----------------

// src_enc (S,B,H) f32 -> src_t (B,S,H) bf16
__global__ void k_conv_src(const float* __restrict__ src, us* __restrict__ dst) {
  const int total = S_LEN * BATCH * 64;       // 8-elem chunks, dest-linear
  int i = blockIdx.x * blockDim.x + threadIdx.x;
  int stride = gridDim.x * blockDim.x;
  for (; i < total; i += stride) {
    int c = i & 63, s = (i >> 6) & 255, b = i >> 14;
    const float* p = src + ((size_t)s * BATCH + b) * NH + c * 8;
    float4 v0 = *(const float4*)p;
    float4 v1 = *(const float4*)(p + 4);
    us o[8] = { f2bf(v0.x), f2bf(v0.y), f2bf(v0.z), f2bf(v0.w),
                f2bf(v1.x), f2bf(v1.y), f2bf(v1.z), f2bf(v1.w) };
    *(short8v*)(dst + (size_t)i * 8) = *(const short8v*)o;
  }
}

__global__ void k_conv_w(const float* __restrict__ Wo, const float* __restrict__ Wz,
                         const float* __restrict__ Wr, const float* __restrict__ Wn,
                         const float* __restrict__ Wa, const float* __restrict__ Ws,
                         const float* __restrict__ Wob, const float* __restrict__ Wzb,
                         const float* __restrict__ Wrb, const float* __restrict__ Wnb,
                         us* __restrict__ W1cat, us* __restrict__ Wns,
                         us* __restrict__ Was, us* __restrict__ Wae,
                         us* __restrict__ Wsbf, float* __restrict__ bcat) {
  const int T1 = 2048 * 1280;
  const int T2 = 512 * 512;
  const int total = T1 + 4 * T2 + 2048;
  int i = blockIdx.x * blockDim.x + threadIdx.x;
  int stride = gridDim.x * blockDim.x;
  for (; i < total; i += stride) {
    int idx = i;
    if (idx < T1) {
      int row = idx / 1280, col = idx - row * 1280;
      float v;
      if      (row < 512)  v = Wo[row * 1280 + col];
      else if (row < 1024) v = Wz[(row - 512) * 1280 + col];
      else if (row < 1536) v = Wr[(row - 1024) * 1280 + col];
      else {
        int g = row - 1536;
        v = (col >= 256 && col < 768) ? 0.f : Wn[g * 1280 + col];
      }
      W1cat[idx] = f2bf(v);
    } else if ((idx -= T1) < T2) {
      int g = idx >> 9, j = idx & 511;
      Wns[idx] = f2bf(Wn[g * 1280 + 256 + j]);
    } else if ((idx -= T2) < T2) {
      int g = idx >> 9, h = idx & 511;
      Was[idx] = f2bf(Wa[g * 1024 + h]);
    } else if ((idx -= T2) < T2) {
      int g = idx >> 9, h = idx & 511;
      Wae[idx] = f2bf(Wa[g * 1024 + 512 + h]);
    } else if ((idx -= T2) < T2) {
      Wsbf[idx] = f2bf(Ws[idx]);
    } else {
      idx -= T2;
      bcat[idx] = (idx < 512) ? Wob[idx]
                : (idx < 1024) ? Wzb[idx - 512]
                : (idx < 1536) ? Wrb[idx - 1024]
                               : Wnb[idx - 1536];
    }
  }
}

__global__ void k_emb(const int* __restrict__ tgt, const float* __restrict__ table,
                      us* __restrict__ emb) {
  const int total = NSTEPS * BATCH * NE;
  int i = blockIdx.x * blockDim.x + threadIdx.x;
  int stride = gridDim.x * blockDim.x;
  for (; i < total; i += stride) {
    int e  = i & (NE - 1);
    int tb = i >> 8;
    int sym = tgt[tb];
    emb[i] = f2bf(table[sym * NE + e]);
  }
}

// ---------------- 8-wave MFMA GEMM tile: 64 rows x 128 cols, BK=64 ----------------
template<int EPI>
__device__ __forceinline__ void gemm_tile(
    char* smem, int m0, int n0,
    const us* __restrict__ A0, const us* __restrict__ A1, const us* __restrict__ A2,
    int lda, const us* __restrict__ Bw, int ldb, int K,
    const float* __restrict__ bias, float* __restrict__ f0, float* __restrict__ f1,
    float* __restrict__ f2, us* __restrict__ g0, const float* __restrict__ sf) {
  const int tid = threadIdx.x;
  char* As0 = smem;               // 2 x 8192
  char* Bs0 = smem + 16384;       // 2 x 16384
  const int arow = tid >> 3, ac = (tid & 7) * 8;     // A: 64 rows x 64 cols
  const int brow = tid >> 2, bc = (tid & 3) * 16;    // B: 128 rows x 64 cols
  short8v ar, br0, br1;

  auto loadT = [&](int k0) {
    if (EPI == EPI_STEP1) {
      const int cc = k0 + ac;
      const us* p = (cc < 256) ? A0 + (size_t)(m0 + arow) * 256 + cc
                  : (cc < 768) ? A1 + (size_t)(m0 + arow) * 512 + (cc - 256)
                               : A2 + (size_t)(m0 + arow) * 512 + (cc - 768);
      ar = *(const short8v*)p;
    } else {
      ar = *(const short8v*)(A0 + (size_t)(m0 + arow) * lda + (k0 + ac));
    }
    const us* q = Bw + (size_t)(n0 + brow) * ldb + (k0 + bc);
    br0 = *(const short8v*)q;
    br1 = *(const short8v*)(q + 8);
  };
  auto stage = [&](int buf) {
    *(short8v*)(As0 + buf * 8192 + arow * 128 + ((ac * 2) ^ ((arow & 7) << 4))) = ar;
    char* bb = Bs0 + buf * 16384 + brow * 128;
    const int sw = (brow & 7) << 4;
    *(short8v*)(bb + ((bc * 2) ^ sw)) = br0;
    *(short8v*)(bb + ((bc * 2 + 16) ^ sw)) = br1;
  };

  const int lane = tid & 63, wave = tid >> 6;
  const int wm = (wave >> 2) * 32, wn = (wave & 3) * 32;
  const int fr = lane & 15, kq = lane >> 4;
  const int ra0 = wm + fr, ra1 = ra0 + 16;
  const int rb0 = wn + fr, rb1 = rb0 + 16;
  float4v acc00 = {0,0,0,0}, acc01 = {0,0,0,0}, acc10 = {0,0,0,0}, acc11 = {0,0,0,0};

  loadT(0);
  stage(0);
  const int nit = K >> 6;
  for (int it = 0; it < nit; ++it) {
    __syncthreads();
    if (it + 1 < nit) loadT((it + 1) << 6);
    const char* ab = As0 + (it & 1) * 8192;
    const char* bb = Bs0 + (it & 1) * 16384;
    #pragma unroll
    for (int ks = 0; ks < 2; ++ks) {
      const int cb = ks * 64 + kq * 16;
      short8v a0 = *(const short8v*)(ab + ra0 * 128 + (cb ^ ((ra0 & 7) << 4)));
      short8v a1 = *(const short8v*)(ab + ra1 * 128 + (cb ^ ((ra1 & 7) << 4)));
      short8v b0 = *(const short8v*)(bb + rb0 * 128 + (cb ^ ((rb0 & 7) << 4)));
      short8v b1 = *(const short8v*)(bb + rb1 * 128 + (cb ^ ((rb1 & 7) << 4)));
      acc00 = __builtin_amdgcn_mfma_f32_16x16x32_bf16(a0, b0, acc00, 0, 0, 0);
      acc01 = __builtin_amdgcn_mfma_f32_16x16x32_bf16(a0, b1, acc01, 0, 0, 0);
      acc10 = __builtin_amdgcn_mfma_f32_16x16x32_bf16(a1, b0, acc10, 0, 0, 0);
      acc11 = __builtin_amdgcn_mfma_f32_16x16x32_bf16(a1, b1, acc11, 0, 0, 0);
    }
    if (it + 1 < nit) stage((it + 1) & 1);
  }

  #pragma unroll
  for (int am = 0; am < 2; ++am) {
    #pragma unroll
    for (int bn = 0; bn < 2; ++bn) {
      float4v a = am ? (bn ? acc11 : acc10) : (bn ? acc01 : acc00);
      #pragma unroll
      for (int r = 0; r < 4; ++r) {
        const int rowO = m0 + wm + am * 16 + kq * 4 + r;
        const int colO = n0 + wn + bn * 16 + fr;
        float v = a[r];
        if (EPI == EPI_S0) {
          float tv = tanh2(v + bias[colO]);
          f0[(size_t)rowO * 512 + colO] = tv;
          g0[(size_t)rowO * 512 + colO] = f2bf(tv);
        } else if (EPI == EPI_EPROJ) {
          g0[(size_t)rowO * 512 + colO] = f2bf(v + bias[colO]);
        } else { // EPI_STEP1
          v += bias[colO];
          const int q = colO >> 9, j = colO & 511;
          const size_t idx = (size_t)rowO * 512 + j;
          if      (q == 0) f0[idx] = v;                       // dec_outputs[t]
          else if (q == 1) f1[idx] = sigm(v);                 // zi
          else if (q == 2) g0[idx] = f2bf(sigm(v) * sf[idx]); // xn = ri*s
          else             f2[idx] = v;                       // npart (incl Wn_b)
        }
      }
    }
  }
}

template<int EPI>
__global__ __launch_bounds__(512, 2) void k_gemm(
    const us* __restrict__ A0, int lda, const us* __restrict__ Bw, int ldb, int K,
    const float* __restrict__ bias, float* __restrict__ f0, us* __restrict__ g0) {
  __shared__ alignas(16) char smem[49152];
  gemm_tile<EPI>(smem, blockIdx.x * 64, blockIdx.y * 128,
                 A0, nullptr, nullptr, lda, Bw, ldb, K,
                 bias, f0, nullptr, nullptr, g0, nullptr);
}

__global__ __launch_bounds__(512, 2) void k_step1(
    const us* __restrict__ emb, const us* __restrict__ sbf, const us* __restrict__ cibf,
    const us* __restrict__ W1cat, const float* __restrict__ bcat,
    float* __restrict__ dec_out_t, float* __restrict__ zi, float* __restrict__ npart,
    us* __restrict__ xn_bf, const float* __restrict__ s_f32) {
  __shared__ alignas(16) char smem[49152];
  gemm_tile<EPI_STEP1>(smem, blockIdx.x * 64, blockIdx.y * 128,
                       emb, sbf, cibf, 0, W1cat, 1280, 1280,
                       bcat, dec_out_t, zi, npart, xn_bf, s_f32);
}

// ------- K_A: GRU-finish(t-1) + sWa matvec + attention, one block per batch -------
__global__ __launch_bounds__(1024, 1) void k_attn2(
    const us* __restrict__ ep,        // (B,S,H) bf16
    const us* __restrict__ srcb,      // (B,S,H) bf16
    const us* __restrict__ Was,       // (512,512) bf16
    const us* __restrict__ Wns,       // (512,512) bf16
    const float* __restrict__ vaw,    // (NH,)
    const int* __restrict__ slen,     // (B,)
    const float* __restrict__ zi,     // (B,NH) z_{t-1}
    const float* __restrict__ npart,  // (B,NH) n-preact partial
    const us* __restrict__ xn_bf,     // (B,NH) r*s
    float* __restrict__ s_f32, us* __restrict__ s_bf,
    float* __restrict__ dec_states_t, // (B,NH) <- s_t
    float* __restrict__ attn_out,     // (B,S)  <- ai_t
    us* __restrict__ ci_bf,           // (B,NH)
    int has_gru) {
  __shared__ float xnf[512];
  __shared__ float sfl[512];
  __shared__ float q2l[512];
  __shared__ float ei[S_LEN];
  __shared__ float ai[S_LEN];
  __shared__ float red[16];
  __shared__ float red16[16][512];    // 32 KB

  const int b = blockIdx.x, tid = threadIdx.x;
  const int lane = tid & 63, wave = tid >> 6;   // 16 waves
  const int g0l = lane * 8;
  const int h = tid >> 1, half = tid & 1;
  const int len = slen[b];

  // stage xn as float
  if (has_gru && tid < 512) xnf[tid] = bf2f(xn_bf[b * 512 + tid]);
  __syncthreads();

  // ---- GRU finish (step t-1) + state write ----
  {
    float s_new;
    if (has_gru) {
      const us* wr = Wns + (size_t)h * 512 + half * 256;
      float acc = 0.f;
      #pragma unroll
      for (int i = 0; i < 32; i++) {
        short8v w8 = *(const short8v*)(wr + i * 8);
        #pragma unroll
        for (int j = 0; j < 8; j++)
          acc = __builtin_fmaf(bf2f((us)w8[j]), xnf[half * 256 + i * 8 + j], acc);
      }
      acc += __shfl_xor(acc, 1, 64);            // combine k-halves (lane pair)
      float z  = zi[b * 512 + h];
      float so = s_f32[b * 512 + h];
      float nv = tanh2(npart[b * 512 + h] + acc);
      s_new = (1.f - z) * so + z * nv;
    } else {
      s_new = s_f32[b * 512 + h];
    }
    if (half == 0) {
      sfl[h] = s_new;
      dec_states_t[b * 512 + h] = s_new;
      if (has_gru) {
        s_f32[b * 512 + h] = s_new;
        s_bf[b * 512 + h]  = f2bf(s_new);
      }
    }
  }
  __syncthreads();

  // ---- sWa matvec: q2l[h] = 2 * (s_t . Was[h,:]) ----
  {
    const us* wr = Was + (size_t)h * 512 + half * 256;
    float acc = 0.f;
    #pragma unroll
    for (int i = 0; i < 32; i++) {
      short8v w8 = *(const short8v*)(wr + i * 8);
      #pragma unroll
      for (int j = 0; j < 8; j++)
        acc = __builtin_fmaf(bf2f((us)w8[j]), sfl[half * 256 + i * 8 + j], acc);
    }
    acc += __shfl_xor(acc, 1, 64);
    if (half == 0) q2l[h] = 2.f * acc;
  }
  __syncthreads();

  // ---- scores: ei[s] = sumv - sum_h 2*va[h]/(e^{2(ep+q)}+1), 4-deep prefetch ----
  {
    float vv2[8]; float sumv = 0.f;
    const float* vp = vaw + g0l;
    #pragma unroll
    for (int j = 0; j < 8; j++) { vv2[j] = 2.f * vp[j]; sumv += vp[j]; }
    #pragma unroll
    for (int off = 32; off > 0; off >>= 1) sumv += __shfl_xor(sumv, off, 64);
    float q2[8];
    #pragma unroll
    for (int j = 0; j < 8; j++) q2[j] = q2l[g0l + j];

    const us* epb = ep + ((size_t)b * S_LEN) * NH + g0l;
    short8v c0, c1, c2, c3, n0, n1, n2, n3;
    c0 = *(const short8v*)(epb + (size_t)(wave +  0) * NH);
    c1 = *(const short8v*)(epb + (size_t)(wave + 16) * NH);
    c2 = *(const short8v*)(epb + (size_t)(wave + 32) * NH);
    c3 = *(const short8v*)(epb + (size_t)(wave + 48) * NH);
    #pragma unroll
    for (int cch = 0; cch < 4; cch++) {
      if (cch < 3) {
        const us* nb = epb + (size_t)(wave + 64 * (cch + 1)) * NH;
        n0 = *(const short8v*)(nb);
        n1 = *(const short8v*)(nb + 16 * NH);
        n2 = *(const short8v*)(nb + 32 * NH);
        n3 = *(const short8v*)(nb + 48 * NH);
      }
      #pragma unroll
      for (int k = 0; k < 4; k++) {
        short8v v = k == 0 ? c0 : k == 1 ? c1 : k == 2 ? c2 : c3;
        int s = wave + 64 * cch + 16 * k;
        float acc = 0.f;
        #pragma unroll
        for (int j = 0; j < 8; j++) {
          float arg = __builtin_fmaf(bf2f((us)v[j]), 2.f, q2[j]);
          acc = __builtin_fmaf(vv2[j],
                __builtin_amdgcn_rcpf(__expf(arg) + 1.f), acc);
        }
        #pragma unroll
        for (int off = 32; off > 0; off >>= 1) acc += __shfl_xor(acc, off, 64);
        if (lane == 0) ei[s] = (s < len) ? (sumv - acc) : -3.0e38f;
      }
      c0 = n0; c1 = n1; c2 = n2; c3 = n3;
    }
  }
  __syncthreads();

  // ---- softmax over s (16-wave) ----
  {
    float e = (tid < S_LEN) ? ei[tid] : -3.0e38f;
    float m = e;
    #pragma unroll
    for (int off = 32; off > 0; off >>= 1) m = fmaxf(m, __shfl_xor(m, off, 64));
    if (lane == 0) red[wave] = m;
    __syncthreads();
    m = red[0];
    #pragma unroll
    for (int w = 1; w < 16; w++) m = fmaxf(m, red[w]);
    float p = (tid < S_LEN) ? __expf(e - m) : 0.f;
    float sum = p;
    #pragma unroll
    for (int off = 32; off > 0; off >>= 1) sum += __shfl_xor(sum, off, 64);
    __syncthreads();
    if (lane == 0) red[wave] = sum;
    __syncthreads();
    float tot = red[0];
    #pragma unroll
    for (int w = 1; w < 16; w++) tot += red[w];
    float inv = __builtin_amdgcn_rcpf(tot);
    if (tid < S_LEN) {
      float av = p * inv;
      ai[tid] = av;
      attn_out[(size_t)b * S_LEN + tid] = av;
    }
  }
  __syncthreads();

  // ---- context: ci[h] = sum_s ai[s]*src[b,s,h], 4-deep prefetch ----
  {
    float a8[8] = {0,0,0,0,0,0,0,0};
    const us* sb = srcb + ((size_t)b * S_LEN) * NH + g0l;
    short8v c0, c1, c2, c3, n0, n1, n2, n3;
    c0 = *(const short8v*)(sb + (size_t)(wave +  0) * NH);
    c1 = *(const short8v*)(sb + (size_t)(wave + 16) * NH);
    c2 = *(const short8v*)(sb + (size_t)(wave + 32) * NH);
    c3 = *(const short8v*)(sb + (size_t)(wave + 48) * NH);
    #pragma unroll
    for (int cch = 0; cch < 4; cch++) {
      if (cch < 3) {
        const us* nb = sb + (size_t)(wave + 64 * (cch + 1)) * NH;
        n0 = *(const short8v*)(nb);
        n1 = *(const short8v*)(nb + 16 * NH);
        n2 = *(const short8v*)(nb + 32 * NH);
        n3 = *(const short8v*)(nb + 48 * NH);
      }
      #pragma unroll
      for (int k = 0; k < 4; k++) {
        short8v v = k == 0 ? c0 : k == 1 ? c1 : k == 2 ? c2 : c3;
        float av = ai[wave + 64 * cch + 16 * k];
        #pragma unroll
        for (int j = 0; j < 8; j++)
          a8[j] = __builtin_fmaf(av, bf2f((us)v[j]), a8[j]);
      }
      c0 = n0; c1 = n1; c2 = n2; c3 = n3;
    }
    #pragma unroll
    for (int j = 0; j < 8; j++) red16[wave][g0l + j] = a8[j];
  }
  __syncthreads();
  if (tid < 512) {
    float cv = 0.f;
    #pragma unroll
    for (int w = 0; w < 16; w++) cv += red16[w][tid];
    ci_bf[b * 512 + tid] = f2bf(cv);
  }
}

} // namespace

extern "C" void kernel_launch(void* const* d_in, const int* in_sizes, int n_in,
                              void* d_out, int out_size, void* d_ws, size_t ws_size,
                              hipStream_t stream) {
  const float* src_enc  = (const float*)d_in[0];
  const int*   tgt      = (const int*)d_in[1];
  const int*   slen     = (const int*)d_in[2];
  const float* emb_tab  = (const float*)d_in[3];
  const float* Wsw      = (const float*)d_in[4];
  const float* Wsb      = (const float*)d_in[5];
  const float* Wzw      = (const float*)d_in[6];
  const float* Wzb      = (const float*)d_in[7];
  const float* Wrw      = (const float*)d_in[8];
  const float* Wrb      = (const float*)d_in[9];
  const float* Wnw      = (const float*)d_in[10];
  const float* Wnb      = (const float*)d_in[11];
  const float* Waw      = (const float*)d_in[12];
  const float* Wab      = (const float*)d_in[13];
  const float* vaw      = (const float*)d_in[14];
  const float* Wow      = (const float*)d_in[15];
  const float* Wob      = (const float*)d_in[16];

  char* ws = (char*)d_ws;
  size_t off = 0;
  auto alloc = [&](size_t bytes) -> void* {
    void* p = ws + off;
    off = (off + bytes + 255) & ~(size_t)255;
    return p;
  };
  us*    src_t  = (us*)alloc(SRC_ELEMS * 2);
  us*    ep_t   = (us*)alloc(SRC_ELEMS * 2);
  us*    emb_bf = (us*)alloc((size_t)NSTEPS * BATCH * NE * 2);
  us*    W1cat  = (us*)alloc((size_t)N1 * 1280 * 2);
  us*    Wns    = (us*)alloc((size_t)512 * 512 * 2);
  us*    Was    = (us*)alloc((size_t)512 * 512 * 2);
  us*    Wae    = (us*)alloc((size_t)512 * 512 * 2);
  us*    Wsbf   = (us*)alloc((size_t)512 * 512 * 2);
  float* bcat   = (float*)alloc((size_t)N1 * 4);
  float* s_f32  = (float*)alloc((size_t)BATCH * NH * 4);
  us*    s_bf   = (us*)alloc((size_t)BATCH * NH * 2);
  float* zi     = (float*)alloc((size_t)BATCH * NH * 4);
  float* npart  = (float*)alloc((size_t)BATCH * NH * 4);
  us*    xn_bf  = (us*)alloc((size_t)BATCH * NH * 2);
  us*    ci_bf  = (us*)alloc((size_t)BATCH * NH * 2);

  float* out         = (float*)d_out;
  float* dec_outputs = out;
  float* dec_states  = out + (size_t)NSTEPS * BATCH * NH;
  float* dec_attns   = dec_states + (size_t)NSTEPS * BATCH * NH;

  // ---- prologue ----
  k_conv_src<<<4096, 256, 0, stream>>>(src_enc, src_t);
  k_conv_w<<<2048, 256, 0, stream>>>(Wow, Wzw, Wrw, Wnw, Waw, Wsw,
                                     Wob, Wzb, Wrb, Wnb,
                                     W1cat, Wns, Was, Wae, Wsbf, bcat);
  k_emb<<<2048, 256, 0, stream>>>(tgt, emb_tab, emb_bf);
  // s0 = tanh(src_enc[0] @ Ws^T + Ws_b): src_t rows (b, s=0) at stride S*NH
  k_gemm<EPI_S0><<<dim3(4, 4), 512, 0, stream>>>(
      src_t, S_LEN * NH, Wsbf, 512, 512, Wsb, s_f32, s_bf);
  // ep_t[b,s] = src_t[b,s] @ Wae^T + Wa_b
  k_gemm<EPI_EPROJ><<<dim3(1024, 4), 512, 0, stream>>>(
      src_t, 512, Wae, 512, 512, Wab, nullptr, ep_t);

  // ---- 127 steps x 2 kernels ----
  for (int t = 0; t < NSTEPS; t++) {
    k_attn2<<<BATCH, 1024, 0, stream>>>(
        ep_t, src_t, Was, Wns, vaw, slen, zi, npart, xn_bf,
        s_f32, s_bf, dec_states + (size_t)t * BATCH * NH,
        dec_attns + (size_t)t * BATCH * S_LEN, ci_bf, t > 0 ? 1 : 0);
    k_step1<<<dim3(4, 16), 512, 0, stream>>>(
        emb_bf + (size_t)t * BATCH * NE, s_bf, ci_bf, W1cat, bcat,
        dec_outputs + (size_t)t * BATCH * NH, zi, npart, xn_bf, s_f32);
  }
}